// Round 9
// baseline (174.360 us; speedup 1.0000x reference)
//
#include <hip/hip_runtime.h>

typedef __attribute__((ext_vector_type(4))) float f32x4;
typedef __attribute__((ext_vector_type(8))) short bfrag; // 8 x bf16 in 4 VGPRs

#define NCH 256
#define NBLK 512
#define BN_EPS 1e-5f

__device__ __forceinline__ unsigned short cvt_bf16(float f){
  unsigned u = __float_as_uint(f);
  u += 0x7FFFu + ((u >> 16) & 1u);           // round-to-nearest-even
  return (unsigned short)(u >> 16);
}
__device__ __forceinline__ float bf16tof(unsigned short h){
  return __uint_as_float(((unsigned)h) << 16);
}
__device__ __forceinline__ void split2(const f32x4 va, const f32x4 vb, bfrag& hi, bfrag& lo){
  #pragma unroll
  for (int e = 0; e < 4; ++e){
    unsigned short h0 = cvt_bf16(va[e]);
    hi[e]   = (short)h0;
    lo[e]   = (short)cvt_bf16(va[e] - bf16tof(h0));
    unsigned short h1b = cvt_bf16(vb[e]);
    hi[4+e] = (short)h1b;
    lo[4+e] = (short)cvt_bf16(vb[e] - bf16tof(h1b));
  }
}

#define GLOAD_LDS16(gp, lp) \
  __builtin_amdgcn_global_load_lds((const __attribute__((address_space(1))) unsigned*)(gp), \
                                   (__attribute__((address_space(3))) unsigned*)(lp), 16, 0, 0)

// ---- K0: pack W1 (hi-only, K 440->448) fragment-order; pack W2 in PERMUTED-K order
//      (so GEMM2's A-frags come straight from GEMM1's accumulators); zero gsum+cnt ----
__global__ void k_prep(const float* __restrict__ W1, const float* __restrict__ W2,
                       unsigned short* __restrict__ W1p, unsigned short* __restrict__ W2p,
                       float* __restrict__ gsum){
  int t = blockIdx.x * 256 + threadIdx.x;
  if (t < 14 * 8192){
    int e = t & 7, l = (t >> 3) & 63, c = (t >> 9) & 15, s = t >> 13;
    int chan = c * 16 + (l & 15);
    int k = s * 32 + (l >> 4) * 8 + e;
    float v = (k < 440) ? W1[chan * 440 + k] : 0.f;
    W1p[s * 8192 + c * 512 + l * 8 + e] = cvt_bf16(v);
  }
  if (t < 16384){
    // W2p[s2][c2][lane][e'] = W2[j2 = c2*16+(l&15)][ch = sigma(s2, l>>4, e')]
    // sigma(s2,g,e') = (2*s2 + (e'>>2))*16 + g*4 + (e'&3)  -- bijective over 256 ch
    int e = t & 7, l = (t >> 3) & 63, c2 = (t >> 9) & 3, s2 = t >> 11;
    int j2 = c2 * 16 + (l & 15);
    int ch = (2 * s2 + (e >> 2)) * 16 + ((l >> 4) << 2) + (e & 3);
    W2p[t] = cvt_bf16(W2[j2 * 256 + ch]);
  }
  if (t < 516) gsum[t] = 0.f;   // 512 sums + spin counter (+pad)
}

__device__ __forceinline__ void stage_w(const char* __restrict__ wsrc, char* smem,
                                        int S, int BUF, int w, int l){
  #pragma unroll
  for (int r = 0; r < 4; ++r)
    GLOAD_LDS16(wsrc + S * 16384 + (w * 4 + r) * 1024 + l * 16,
                smem + BUF * 16384 + (w * 4 + r) * 1024);
}

// ---- K1: fully fused: gather + GEMM1-swapped + stats + SPIN grid barrier + BN +
//      GEMM2 (A-frags lane-local from acc) + GEMM3/4.  512 blocks x 256 thr =
//      exactly 2 blocks/CU x 256 CUs -> co-residency capacity-guaranteed. ----
__global__ __launch_bounds__(256, 2) void k_fused(
    const int* __restrict__ state, const int* __restrict__ counts, const int* __restrict__ mp,
    const float* __restrict__ embed, const float* __restrict__ stab, const float* __restrict__ ctab,
    const unsigned short* __restrict__ W1p, const float* __restrict__ b1,
    const unsigned short* __restrict__ W2p, const float* __restrict__ b2,
    const float* __restrict__ W3, const float* __restrict__ b3,
    const float* __restrict__ W4, const float* __restrict__ b4,
    const float* __restrict__ gamma, const float* __restrict__ beta,
    float* __restrict__ gsum, float* __restrict__ out)
{
  __shared__ __align__(16) char lds[57856];
  char*  smem   = lds;                        // [0,32768): W1 dbuf (ph1) / W2p (ph2)
  int*   mp_lds = (int*)(lds + 32768);        // [32768,57856): mp[128][49] (ph1)
  float* wsum   = (float*)(lds + 32768);      // [32768,36864): stats (between phases)
  float* wsq    = (float*)(lds + 36864);      // [36864,40960)
  float* ssl    = (float*)(lds + 32768);      // [32768,34816): BN scale/shift (ph2)
  float* h2l    = (float*)(lds + 34816);      // [34816,51456): h2 tiles (ph2)
  unsigned* cnt = (unsigned*)(gsum + 512);

  const int tid = threadIdx.x;
  const int w  = tid >> 6;
  const int l  = tid & 63;
  const int lr = l & 15;
  const int g  = l >> 4;
  const int rowbase = blockIdx.x * 128 + w * 32;
  const int arow0 = rowbase + lr;
  const int arow1 = rowbase + 16 + lr;

  const int st0 = state[arow0] * 32, st1 = state[arow1] * 32;
  const int ct0 = counts[arow0] * 16, ct1 = counts[arow1] * 16;
  const char* wsrc = (const char*)W1p;

  // stage this block's mp slice (coalesced 25088 B)
  {
    const char* mpsrc = (const char*)(mp + (size_t)blockIdx.x * 6272);
    #pragma unroll
    for (int it = 0; it < 7; ++it){
      int idx = it * 256 + tid;
      if (idx < 1568)
        GLOAD_LDS16(mpsrc + idx * 16, (char*)mp_lds + idx * 16);
    }
  }

  f32x4 xva[3][2], xvb[3][2];   // 3-slot ring: x(s), x(s+1), x(s+2)
  f32x4 acc0[16], acc1[16];
  #pragma unroll
  for (int i = 0; i < 16; ++i){ acc0[i] = (f32x4){0.f,0.f,0.f,0.f}; acc1[i] = acc0[i]; }

  #define ISSUE_X(S) do {                                            \
    const float *p0_, *p1_;                                          \
    if ((S) == 0){ p0_ = stab + st0 + g * 8; p1_ = stab + st1 + g * 8; } \
    else if ((S) == 1 && g < 2){                                     \
      p0_ = ctab + ct0 + g * 8; p1_ = ctab + ct1 + g * 8;            \
    } else {                                                         \
      int m_ = 4 * (S) + g - 6;                                      \
      m_ = m_ < 0 ? 0 : (m_ > 48 ? 48 : m_);                         \
      p0_ = embed + ((mp_lds[(w * 32 + lr) * 49 + m_]      & 0xFFFFFF) << 3); \
      p1_ = embed + ((mp_lds[(w * 32 + 16 + lr) * 49 + m_] & 0xFFFFFF) << 3); \
    }                                                                \
    xva[(S)%3][0] = *(const f32x4*)p0_;  xvb[(S)%3][0] = *(const f32x4*)(p0_ + 4); \
    xva[(S)%3][1] = *(const f32x4*)p1_;  xvb[(S)%3][1] = *(const f32x4*)(p1_ + 4); \
  } while(0)

  // ---- prologue: mp+W(0)+x(0) issued; full drain; barrier (mp_lds valid); x(1) ----
  stage_w(wsrc, smem, 0, 0, w, l);
  ISSUE_X(0);
  asm volatile("s_waitcnt vmcnt(0)" ::: "memory");
  __builtin_amdgcn_sched_barrier(0);
  __builtin_amdgcn_s_barrier();
  ISSUE_X(1);
  asm volatile("" ::: "memory");
  __builtin_amdgcn_sched_barrier(0);

  bfrag ahi0, alo0, ahi1, alo1;

  #pragma unroll
  for (int s = 0; s < 14; ++s){
    // [A] stage W(s+1) (in flight across barriers)
    if (s < 13) stage_w(wsrc, smem, s + 1, (s + 1) & 1, w, l);
    asm volatile("" ::: "memory");
    __builtin_amdgcn_sched_barrier(0);

    // [B] consume x(s) -> frags; issue x(s+2)
    {
      f32x4 va0 = xva[s % 3][0], vb0 = xvb[s % 3][0];
      f32x4 va1 = xva[s % 3][1], vb1 = xvb[s % 3][1];
      if (s == 13 && g == 3){                      // K-pad 440..447 -> zeros
        va0 = (f32x4){0.f,0.f,0.f,0.f}; vb0 = va0; va1 = va0; vb1 = va0;
      }
      split2(va0, vb0, ahi0, alo0);
      split2(va1, vb1, ahi1, alo1);
    }
    if (s < 12) ISSUE_X(s + 2);

    // [C] retire stage(s): in-order vmcnt; newer outstanding = 12 in steady state
    __builtin_amdgcn_sched_barrier(0);
    if (s <= 11)      asm volatile("s_waitcnt vmcnt(12)" ::: "memory");
    else if (s == 12) asm volatile("s_waitcnt vmcnt(8)"  ::: "memory");
    else              asm volatile("s_waitcnt vmcnt(0)"  ::: "memory");
    __builtin_amdgcn_sched_barrier(0);
    __builtin_amdgcn_s_barrier();

    // [D] MFMA SWAPPED: A = W1 frag (LDS), B = x frag -> acc[ch][row]
    {
      const char* base = smem + (s & 1) * 16384 + l * 16;
      #pragma unroll
      for (int c = 0; c < 16; ++c){
        const bfrag whi = *(const bfrag*)(base + c * 1024);
        acc0[c] = __builtin_amdgcn_mfma_f32_16x16x32_bf16(whi, ahi0, acc0[c], 0, 0, 0);
        acc0[c] = __builtin_amdgcn_mfma_f32_16x16x32_bf16(whi, alo0, acc0[c], 0, 0, 0);
        acc1[c] = __builtin_amdgcn_mfma_f32_16x16x32_bf16(whi, ahi1, acc1[c], 0, 0, 0);
        acc1[c] = __builtin_amdgcn_mfma_f32_16x16x32_bf16(whi, alo1, acc1[c], 0, 0, 0);
      }
    }
    // [E] barrier: buf[s&1] free for stage(s+2)
    __builtin_amdgcn_s_barrier();
  }
  #undef ISSUE_X

  // ---- stage W2p into smem (both W bufs dead); overlaps stats + spin wait ----
  #pragma unroll
  for (int it = 0; it < 8; ++it)
    GLOAD_LDS16((const char*)W2p + (it * 256 + tid) * 16, lds + (it * 256 + tid) * 16);

  // ---- bias + batch stats (acc layout: ch = c*16+g*4+e, row = lr) ----
  #pragma unroll
  for (int c = 0; c < 16; ++c){
    f32x4 bb = *(const f32x4*)(b1 + c * 16 + g * 4);
    acc0[c] += bb;
    acc1[c] += bb;
    #pragma unroll
    for (int e = 0; e < 4; ++e){
      float v0 = acc0[c][e], v1 = acc1[c][e];
      float s = v0 + v1, q = v0 * v0 + v1 * v1;
      s += __shfl_xor(s, 1); q += __shfl_xor(q, 1);
      s += __shfl_xor(s, 2); q += __shfl_xor(q, 2);
      s += __shfl_xor(s, 4); q += __shfl_xor(q, 4);
      s += __shfl_xor(s, 8); q += __shfl_xor(q, 8);
      if (lr == 0){
        int ch = c * 16 + g * 4 + e;
        wsum[w * 256 + ch] = s;
        wsq [w * 256 + ch] = q;
      }
    }
  }
  __syncthreads();
  {
    float s = wsum[tid] + wsum[256 + tid] + wsum[512 + tid] + wsum[768 + tid];
    float q = wsq[tid]  + wsq[256 + tid]  + wsq[512 + tid]  + wsq[768 + tid];
    atomicAdd(&gsum[tid], s);
    atomicAdd(&gsum[256 + tid], q);
  }

  // ---- device-wide spin barrier (all 512 blocks co-resident by capacity) ----
  __threadfence();
  __syncthreads();   // drains this wave's atomics + W2p stage loads (vmcnt 0)
  if (tid == 0){
    __hip_atomic_fetch_add(cnt, 1u, __ATOMIC_ACQ_REL, __HIP_MEMORY_SCOPE_AGENT);
    while (__hip_atomic_load(cnt, __ATOMIC_ACQUIRE, __HIP_MEMORY_SCOPE_AGENT) < NBLK)
      __builtin_amdgcn_s_sleep(2);
  }
  __syncthreads();

  // ---- BN scale/shift (ssl overwrites dead wsum region) ----
  {
    float su = __hip_atomic_load(&gsum[tid],       __ATOMIC_RELAXED, __HIP_MEMORY_SCOPE_AGENT);
    float sq = __hip_atomic_load(&gsum[256 + tid], __ATOMIC_RELAXED, __HIP_MEMORY_SCOPE_AGENT);
    float mu  = su * (1.f / 65536.f);
    float var = sq * (1.f / 65536.f) - mu * mu;
    float sc  = gamma[tid] * rsqrtf(var + BN_EPS);
    ssl[tid]       = sc;
    ssl[256 + tid] = beta[tid] - mu * sc;
  }
  __syncthreads();

  const float b4v = b4[0];

  // ---- GEMM2 (A-frags lane-local from acc via permuted-K W2p) + GEMM3/4, per tile ----
#define TAIL_TILE(ACC, TOFF) do {                                                  \
    f32x4 acc2[4];                                                                 \
    acc2[0] = (f32x4){0.f,0.f,0.f,0.f};                                            \
    acc2[1] = acc2[0]; acc2[2] = acc2[0]; acc2[3] = acc2[0];                       \
    _Pragma("unroll")                                                              \
    for (int s2 = 0; s2 < 8; ++s2){                                                \
      bfrag ahi, alo;                                                              \
      _Pragma("unroll")                                                            \
      for (int hh = 0; hh < 2; ++hh){                                              \
        const int c = 2 * s2 + hh;                                                 \
        f32x4 sc = *(const f32x4*)(ssl + c * 16 + g * 4);                          \
        f32x4 sh = *(const f32x4*)(ssl + 256 + c * 16 + g * 4);                    \
        _Pragma("unroll")                                                          \
        for (int e = 0; e < 4; ++e){                                               \
          float x = ACC[c][e] * sc[e] + sh[e];                                     \
          unsigned short h0 = cvt_bf16(x);                                         \
          ahi[hh * 4 + e] = (short)h0;                                             \
          alo[hh * 4 + e] = (short)cvt_bf16(x - bf16tof(h0));                      \
        }                                                                          \
      }                                                                            \
      const char* wb = smem + s2 * 4096 + l * 16;                                  \
      _Pragma("unroll")                                                            \
      for (int c2 = 0; c2 < 4; ++c2){                                              \
        const bfrag bh = *(const bfrag*)(wb + c2 * 1024);                          \
        acc2[c2] = __builtin_amdgcn_mfma_f32_16x16x32_bf16(ahi, bh, acc2[c2],0,0,0); \
        acc2[c2] = __builtin_amdgcn_mfma_f32_16x16x32_bf16(alo, bh, acc2[c2],0,0,0); \
      }                                                                            \
    }                                                                              \
    float* hw = h2l + w * 1040;                                                    \
    _Pragma("unroll")                                                              \
    for (int c2 = 0; c2 < 4; ++c2){                                                \
      const int j = c2 * 16 + lr;                                                  \
      const float bb2 = b2[j];                                                     \
      _Pragma("unroll")                                                            \
      for (int e = 0; e < 4; ++e){                                                 \
        float h = acc2[c2][e] + bb2;                                               \
        hw[(g * 4 + e) * 65 + j] = h > 0.f ? h : 0.f;                              \
      }                                                                            \
    }                                                                              \
    float a3[4];                                                                   \
    _Pragma("unroll")                                                              \
    for (int t3 = 0; t3 < 4; ++t3) a3[t3] = b3[g * 4 + t3];                        \
    _Pragma("unroll 4")                                                            \
    for (int k = 0; k < 64; ++k){                                                  \
      float hv = hw[lr * 65 + k];                                                  \
      _Pragma("unroll")                                                            \
      for (int t3 = 0; t3 < 4; ++t3) a3[t3] += hv * W3[(g * 4 + t3) * 64 + k];     \
    }                                                                              \
    float p = 0.f;                                                                 \
    _Pragma("unroll")                                                              \
    for (int t3 = 0; t3 < 4; ++t3){                                                \
      float h = a3[t3] > 0.f ? a3[t3] : 0.f;                                       \
      p += h * W4[g * 4 + t3];                                                     \
    }                                                                              \
    p += __shfl_xor(p, 16);                                                        \
    p += __shfl_xor(p, 32);                                                        \
    if (l < 16) out[rowbase + (TOFF) + lr] = p + b4v;                              \
  } while (0)

  TAIL_TILE(acc0, 0);
  TAIL_TILE(acc1, 16);
#undef TAIL_TILE
}

extern "C" void kernel_launch(void* const* d_in, const int* in_sizes, int n_in,
                              void* d_out, int out_size, void* d_ws, size_t ws_size,
                              hipStream_t stream){
  const int*   state = (const int*)d_in[0];
  const int*   counts= (const int*)d_in[1];
  const int*   mp    = (const int*)d_in[2];
  const float* embed = (const float*)d_in[3];
  const float* stab  = (const float*)d_in[4];
  const float* ctab  = (const float*)d_in[5];
  const float* W1    = (const float*)d_in[6];
  const float* b1    = (const float*)d_in[7];
  const float* gamma = (const float*)d_in[8];
  const float* beta  = (const float*)d_in[9];
  const float* W2    = (const float*)d_in[10];
  const float* b2    = (const float*)d_in[11];
  const float* W3    = (const float*)d_in[12];
  const float* b3    = (const float*)d_in[13];
  const float* W4    = (const float*)d_in[14];
  const float* b4    = (const float*)d_in[15];
  float* out = (float*)d_out;

  char* ws = (char*)d_ws;
  float* gsum          = (float*)(ws);                          // 512 sums + cnt
  unsigned short* W1p  = (unsigned short*)(ws + 4096);          // 224 KiB
  unsigned short* W2p  = (unsigned short*)(ws + 4096 + 229376); // 32 KiB

  k_prep <<<448, 256, 0, stream>>>(W1, W2, W1p, W2p, gsum);
  k_fused<<<NBLK, 256, 0, stream>>>(state, counts, mp, embed, stab, ctab,
                                    W1p, b1, W2p, b2, W3, b3, W4, b4,
                                    gamma, beta, gsum, out);
}

// Round 10
// 124.022 us; speedup vs baseline: 1.4059x; 1.4059x over previous
//
#include <hip/hip_runtime.h>

typedef __attribute__((ext_vector_type(4))) float f32x4;
typedef __attribute__((ext_vector_type(8))) short bfrag; // 8 x bf16 in 4 VGPRs

#define NCH 256
#define BN_EPS 1e-5f

__device__ __forceinline__ unsigned short cvt_bf16(float f){
  unsigned u = __float_as_uint(f);
  u += 0x7FFFu + ((u >> 16) & 1u);           // round-to-nearest-even
  return (unsigned short)(u >> 16);
}
__device__ __forceinline__ float bf16tof(unsigned short h){
  return __uint_as_float(((unsigned)h) << 16);
}
__device__ __forceinline__ void split2(const f32x4 va, const f32x4 vb, bfrag& hi, bfrag& lo){
  #pragma unroll
  for (int e = 0; e < 4; ++e){
    unsigned short h0 = cvt_bf16(va[e]);
    hi[e]   = (short)h0;
    lo[e]   = (short)cvt_bf16(va[e] - bf16tof(h0));
    unsigned short h1b = cvt_bf16(vb[e]);
    hi[4+e] = (short)h1b;
    lo[4+e] = (short)cvt_bf16(vb[e] - bf16tof(h1b));
  }
}

#define GLOAD_LDS16(gp, lp) \
  __builtin_amdgcn_global_load_lds((const __attribute__((address_space(1))) unsigned*)(gp), \
                                   (__attribute__((address_space(3))) unsigned*)(lp), 16, 0, 0)

// ---- K0: pack W1 (hi-only, K 440->448) and W2 (hi-only) into MFMA fragment order;
//      zero gsum ----
__global__ void k_prep(const float* __restrict__ W1, const float* __restrict__ W2,
                       unsigned short* __restrict__ W1p, unsigned short* __restrict__ W2p,
                       float* __restrict__ gsum){
  int t = blockIdx.x * 256 + threadIdx.x;
  if (t < 14 * 8192){
    int e = t & 7, l = (t >> 3) & 63, c = (t >> 9) & 15, s = t >> 13;
    int chan = c * 16 + (l & 15);
    int k = s * 32 + (l >> 4) * 8 + e;
    float v = (k < 440) ? W1[chan * 440 + k] : 0.f;
    W1p[s * 8192 + c * 512 + l * 8 + e] = cvt_bf16(v);
  }
  if (t < 16384){
    int e = t & 7, l = (t >> 3) & 63, c = (t >> 9) & 3, s = t >> 11;
    int chan = c * 16 + (l & 15);
    int k = s * 32 + (l >> 4) * 8 + e;
    W2p[s * 2048 + c * 512 + l * 8 + e] = cvt_bf16(W2[chan * 256 + k]);
  }
  if (t < 512) gsum[t] = 0.f;
}

__device__ __forceinline__ void stage_w(const char* __restrict__ wsrc, char* smem,
                                        int S, int BUF, int w, int l){
  #pragma unroll
  for (int r = 0; r < 4; ++r)
    GLOAD_LDS16(wsrc + S * 16384 + (w * 4 + r) * 1024 + l * 16,
                smem + BUF * 16384 + (w * 4 + r) * 1024);
}

// ---- K1: gather + GEMM1 (2-pass split-bf16 MFMA, 2-deep gather ring) + h1(bf16)
//      + batch-stat atomics.  64-row blocks, 1 tile/wave, 3 blocks/CU (concurrency
//      experiment: +50% independent gather streams + tail load-balancing). ----
// 1024 blocks x 256 thr (4 waves); wave w: rows [blk*64 + w*16, +16).
__global__ __launch_bounds__(256, 3) void k_gemm1(
    const int* __restrict__ state, const int* __restrict__ counts, const int* __restrict__ mp,
    const float* __restrict__ embed, const float* __restrict__ stab, const float* __restrict__ ctab,
    const unsigned short* __restrict__ W1p, const float* __restrict__ b1,
    unsigned short* __restrict__ h1b, float* __restrict__ gsum)
{
  __shared__ __align__(16) char smem[2 * 16384];     // 32 KiB W double-buffer
  __shared__ __align__(16) int  mp_lds[3136];        // 12.25 KiB mp[64][49]
  float* wsum = (float*)smem;                        // aliases dead W-dbuf post-loop
  float* wsq  = (float*)(smem + 4096);

  const int tid = threadIdx.x;
  const int w  = tid >> 6;
  const int l  = tid & 63;
  const int lr = l & 15;
  const int g  = l >> 4;
  const int rowbase = blockIdx.x * 64 + w * 16;
  const int arow0 = rowbase + lr;

  const int st0 = state[arow0] * 32;
  const int ct0 = counts[arow0] * 16;
  const char* wsrc = (const char*)W1p;

  // stage this block's mp slice (coalesced 12544 B = 784 x 16B)
  {
    const char* mpsrc = (const char*)(mp + (size_t)blockIdx.x * 3136);
    #pragma unroll
    for (int it = 0; it < 4; ++it){
      int idx = it * 256 + tid;
      if (idx < 784)
        GLOAD_LDS16(mpsrc + idx * 16, (char*)mp_lds + idx * 16);
    }
  }

  f32x4 xva[3], xvb[3];         // 3-slot ring: x(s), x(s+1), x(s+2)
  f32x4 acc0[16];
  #pragma unroll
  for (int i = 0; i < 16; ++i) acc0[i] = (f32x4){0.f,0.f,0.f,0.f};

  // x gather-issue for step S into ring slot S%3 (1 row-tile, 32B = 2 vm loads)
  #define ISSUE_X(S) do {                                            \
    const float *p0_;                                                \
    if ((S) == 0){ p0_ = stab + st0 + g * 8; }                       \
    else if ((S) == 1 && g < 2){ p0_ = ctab + ct0 + g * 8; }         \
    else {                                                           \
      int m_ = 4 * (S) + g - 6;                                      \
      m_ = m_ < 0 ? 0 : (m_ > 48 ? 48 : m_);                         \
      p0_ = embed + ((mp_lds[(w * 16 + lr) * 49 + m_] & 0xFFFFFF) << 3); \
    }                                                                \
    xva[(S)%3] = *(const f32x4*)p0_;  xvb[(S)%3] = *(const f32x4*)(p0_ + 4); \
  } while(0)

  // ---- prologue: mp+W(0)+x(0) issued; full drain; barrier (mp_lds valid); x(1) ----
  stage_w(wsrc, smem, 0, 0, w, l);
  ISSUE_X(0);
  asm volatile("s_waitcnt vmcnt(0)" ::: "memory");
  __builtin_amdgcn_sched_barrier(0);
  __builtin_amdgcn_s_barrier();
  ISSUE_X(1);
  asm volatile("" ::: "memory");
  __builtin_amdgcn_sched_barrier(0);

  bfrag ahi0, alo0;

  #pragma unroll
  for (int s = 0; s < 14; ++s){
    // [A] stage W(s+1) (in flight across barriers)
    if (s < 13) stage_w(wsrc, smem, s + 1, (s + 1) & 1, w, l);
    asm volatile("" ::: "memory");
    __builtin_amdgcn_sched_barrier(0);

    // [B] consume x(s) -> frags; issue x(s+2)
    {
      f32x4 va0 = xva[s % 3], vb0 = xvb[s % 3];
      if (s == 13 && g == 3){                      // K-pad 440..447 -> zeros
        va0 = (f32x4){0.f,0.f,0.f,0.f}; vb0 = va0;
      }
      split2(va0, vb0, ahi0, alo0);
    }
    if (s < 12) ISSUE_X(s + 2);

    // [C] retire stage(s): in-order vmcnt; newer = x(s+1)2 + stage(s+1)4 + x(s+2)2
    __builtin_amdgcn_sched_barrier(0);
    if (s <= 11)      asm volatile("s_waitcnt vmcnt(8)" ::: "memory");
    else if (s == 12) asm volatile("s_waitcnt vmcnt(6)" ::: "memory");
    else              asm volatile("s_waitcnt vmcnt(0)" ::: "memory");
    __builtin_amdgcn_sched_barrier(0);
    __builtin_amdgcn_s_barrier();

    // [D] MFMA on buf[s&1]: 16 conflict-free ds_read_b128, 32 MFMA/step
    {
      const char* base = smem + (s & 1) * 16384 + l * 16;
      #pragma unroll
      for (int c = 0; c < 16; ++c){
        const bfrag bhi = *(const bfrag*)(base + c * 1024);
        acc0[c] = __builtin_amdgcn_mfma_f32_16x16x32_bf16(ahi0, bhi, acc0[c], 0, 0, 0);
        acc0[c] = __builtin_amdgcn_mfma_f32_16x16x32_bf16(alo0, bhi, acc0[c], 0, 0, 0);
      }
    }

    // [E] barrier: buf[s&1] free for stage(s+2)
    __builtin_amdgcn_s_barrier();
  }
  #undef ISSUE_X

  // ---- epilogue: bias, h1(bf16) write (D: row=g*4+e, col=lr), stats -> atomics ----
  // smem is dead from here; wsum/wsq alias it.
  #pragma unroll
  for (int c = 0; c < 16; ++c){
    const int j = c * 16 + lr;
    const float bb = b1[j];
    float s = 0.f, q = 0.f;
    #pragma unroll
    for (int e = 0; e < 4; ++e){
      float h = acc0[c][e] + bb;
      s += h; q += h * h;
      h1b[(rowbase + g * 4 + e) * NCH + j] = cvt_bf16(h);
    }
    s += __shfl_xor(s, 16);  s += __shfl_xor(s, 32);
    q += __shfl_xor(q, 16);  q += __shfl_xor(q, 32);
    if (g == 0){ wsum[w * 256 + j] = s; wsq[w * 256 + j] = q; }
  }
  __syncthreads();
  {
    float s = wsum[tid] + wsum[256 + tid] + wsum[512 + tid] + wsum[768 + tid];
    float q = wsq[tid]  + wsq[256 + tid]  + wsq[512 + tid]  + wsq[768 + tid];
    atomicAdd(&gsum[tid], s);
    atomicAdd(&gsum[256 + tid], q);
  }
}

// ---- K2: BN(from gsum) + GEMM2 (2-pass MFMA, W2 in LDS) + ReLU + GEMM3 + ReLU + GEMM4 ----
// 512 blocks x 256 thr; block = 128 rows; wave w: 2 tiles of 16 rows (reuses staged W2).
__global__ __launch_bounds__(256, 3) void k_tail(
    const unsigned short* __restrict__ h1b, const float* __restrict__ gsum,
    const float* __restrict__ gamma, const float* __restrict__ beta,
    const unsigned short* __restrict__ W2p,
    const float* __restrict__ b2, const float* __restrict__ W3, const float* __restrict__ b3,
    const float* __restrict__ W4, const float* __restrict__ b4,
    float* __restrict__ out)
{
  __shared__ float ssl[512];
  __shared__ __align__(16) short w2s[16384];   // 32 KiB
  __shared__ float h2l[4][16][65];

  const int tid = threadIdx.x;
  const int w  = tid >> 6;
  const int l  = tid & 63;
  const int lr = l & 15;
  const int g  = l >> 4;
  const int rowbase = blockIdx.x * 128 + w * 32;

  // per-channel scale/shift from global sums
  {
    float su = gsum[tid];
    float sq = gsum[256 + tid];
    float mu  = su * (1.f / 65536.f);
    float var = sq * (1.f / 65536.f) - mu * mu;
    float sc  = gamma[tid] * rsqrtf(var + BN_EPS);
    ssl[tid]       = sc;
    ssl[256 + tid] = beta[tid] - mu * sc;
  }
  // stage W2p into LDS (32 KiB, coalesced)
  #pragma unroll
  for (int it = 0; it < 8; ++it)
    GLOAD_LDS16((const char*)W2p + (it * 256 + tid) * 16, (char*)w2s + (it * 256 + tid) * 16);
  __syncthreads();   // drains vmcnt + lgkmcnt

  const float b4v = b4[0];

  #pragma unroll
  for (int t = 0; t < 2; ++t){
    const int rowt = rowbase + t * 16;

    f32x4 acc[4];
    #pragma unroll
    for (int i = 0; i < 4; ++i) acc[i] = (f32x4){0.f, 0.f, 0.f, 0.f};

    #pragma unroll
    for (int s = 0; s < 8; ++s){
      const int kk = s * 32 + g * 8;
      bfrag hv = *(const bfrag*)(h1b + (rowt + lr) * 256 + kk);
      bfrag ahi, alo;
      #pragma unroll
      for (int e = 0; e < 8; ++e){
        float x = fmaf(bf16tof((unsigned short)hv[e]), ssl[kk + e], ssl[256 + kk + e]);
        unsigned short h0 = cvt_bf16(x);
        ahi[e] = (short)h0;
        alo[e] = (short)cvt_bf16(x - bf16tof(h0));
      }
      const char* base = (const char*)w2s + s * 4096 + l * 16;
      #pragma unroll
      for (int c = 0; c < 4; ++c){
        const bfrag bhi = *(const bfrag*)(base + c * 1024);
        acc[c] = __builtin_amdgcn_mfma_f32_16x16x32_bf16(ahi, bhi, acc[c], 0, 0, 0);
        acc[c] = __builtin_amdgcn_mfma_f32_16x16x32_bf16(alo, bhi, acc[c], 0, 0, 0);
      }
    }

    #pragma unroll
    for (int c = 0; c < 4; ++c){
      int j = c * 16 + lr;
      float bb = b2[j];
      #pragma unroll
      for (int e = 0; e < 4; ++e){
        float h = acc[c][e] + bb;
        h2l[w][g * 4 + e][j] = h > 0.f ? h : 0.f;
      }
    }

    float a3[4];
    #pragma unroll
    for (int t3 = 0; t3 < 4; ++t3) a3[t3] = b3[g * 4 + t3];
    #pragma unroll 4
    for (int k = 0; k < 64; ++k){
      float hv = h2l[w][lr][k];
      #pragma unroll
      for (int t3 = 0; t3 < 4; ++t3) a3[t3] += hv * W3[(g * 4 + t3) * 64 + k];
    }

    float p = 0.f;
    #pragma unroll
    for (int t3 = 0; t3 < 4; ++t3){
      float h = a3[t3] > 0.f ? a3[t3] : 0.f;
      p += h * W4[g * 4 + t3];
    }
    p += __shfl_xor(p, 16);
    p += __shfl_xor(p, 32);
    if (l < 16) out[rowt + lr] = p + b4v;
  }
}

extern "C" void kernel_launch(void* const* d_in, const int* in_sizes, int n_in,
                              void* d_out, int out_size, void* d_ws, size_t ws_size,
                              hipStream_t stream){
  const int*   state = (const int*)d_in[0];
  const int*   counts= (const int*)d_in[1];
  const int*   mp    = (const int*)d_in[2];
  const float* embed = (const float*)d_in[3];
  const float* stab  = (const float*)d_in[4];
  const float* ctab  = (const float*)d_in[5];
  const float* W1    = (const float*)d_in[6];
  const float* b1    = (const float*)d_in[7];
  const float* gamma = (const float*)d_in[8];
  const float* beta  = (const float*)d_in[9];
  const float* W2    = (const float*)d_in[10];
  const float* b2    = (const float*)d_in[11];
  const float* W3    = (const float*)d_in[12];
  const float* b3    = (const float*)d_in[13];
  const float* W4    = (const float*)d_in[14];
  const float* b4    = (const float*)d_in[15];
  float* out = (float*)d_out;

  char* ws = (char*)d_ws;
  unsigned short* h1bf = (unsigned short*)(ws);              // 32 MiB
  float* gsum          = (float*)(ws + 33554432);            // 2 KiB (sum|sq)
  unsigned short* W1p  = (unsigned short*)(ws + 33558528);   // 224 KiB
  unsigned short* W2p  = (unsigned short*)(ws + 33787904);   // 32 KiB

  k_prep <<<448, 256, 0, stream>>>(W1, W2, W1p, W2p, gsum);
  k_gemm1<<<1024, 256, 0, stream>>>(state, counts, mp, embed, stab, ctab,
                                    W1p, b1, h1bf, gsum);
  k_tail <<<512, 256, 0, stream>>>(h1bf, gsum, gamma, beta, W2p,
                                   b2, W3, b3, W4, b4, out);
}

// Round 11
// 116.955 us; speedup vs baseline: 1.4908x; 1.0604x over previous
//
#include <hip/hip_runtime.h>

typedef __attribute__((ext_vector_type(4))) float f32x4;
typedef __attribute__((ext_vector_type(8))) short bfrag; // 8 x bf16 in 4 VGPRs

#define NCH 256
#define BN_EPS 1e-5f

__device__ __forceinline__ unsigned short cvt_bf16(float f){
  unsigned u = __float_as_uint(f);
  u += 0x7FFFu + ((u >> 16) & 1u);           // round-to-nearest-even
  return (unsigned short)(u >> 16);
}
__device__ __forceinline__ float bf16tof(unsigned short h){
  return __uint_as_float(((unsigned)h) << 16);
}
__device__ __forceinline__ void split2(const f32x4 va, const f32x4 vb, bfrag& hi, bfrag& lo){
  #pragma unroll
  for (int e = 0; e < 4; ++e){
    unsigned short h0 = cvt_bf16(va[e]);
    hi[e]   = (short)h0;
    lo[e]   = (short)cvt_bf16(va[e] - bf16tof(h0));
    unsigned short h1b = cvt_bf16(vb[e]);
    hi[4+e] = (short)h1b;
    lo[4+e] = (short)cvt_bf16(vb[e] - bf16tof(h1b));
  }
}

#define GLOAD_LDS16(gp, lp) \
  __builtin_amdgcn_global_load_lds((const __attribute__((address_space(1))) unsigned*)(gp), \
                                   (__attribute__((address_space(3))) unsigned*)(lp), 16, 0, 0)

// ---- K0: pack W1 (hi-only, K 440->448) and W2 (hi-only) into MFMA fragment order;
//      zero gsum ----
__global__ void k_prep(const float* __restrict__ W1, const float* __restrict__ W2,
                       unsigned short* __restrict__ W1p, unsigned short* __restrict__ W2p,
                       float* __restrict__ gsum){
  int t = blockIdx.x * 256 + threadIdx.x;
  if (t < 14 * 8192){
    int e = t & 7, l = (t >> 3) & 63, c = (t >> 9) & 15, s = t >> 13;
    int chan = c * 16 + (l & 15);
    int k = s * 32 + (l >> 4) * 8 + e;
    float v = (k < 440) ? W1[chan * 440 + k] : 0.f;
    W1p[s * 8192 + c * 512 + l * 8 + e] = cvt_bf16(v);
  }
  if (t < 16384){
    int e = t & 7, l = (t >> 3) & 63, c = (t >> 9) & 3, s = t >> 11;
    int chan = c * 16 + (l & 15);
    int k = s * 32 + (l >> 4) * 8 + e;
    W2p[s * 2048 + c * 512 + l * 8 + e] = cvt_bf16(W2[chan * 256 + k]);
  }
  if (t < 512) gsum[t] = 0.f;
}

__device__ __forceinline__ void stage_w(const char* __restrict__ wsrc, char* smem,
                                        int S, int BUF, int w, int l){
  #pragma unroll
  for (int r = 0; r < 4; ++r)
    GLOAD_LDS16(wsrc + S * 16384 + (w * 4 + r) * 1024 + l * 16,
                smem + BUF * 16384 + (w * 4 + r) * 1024);
}

// ---- K1: gather + GEMM1 (2-pass split-bf16 MFMA, 2-step-deep gather pipeline)
//      + h1(bf16) + batch-stat atomics.  [r5 structure: best measured, 117.9 us] ----
// 512 blocks x 256 thr (4 waves); block = 128 rows; wave w: 32 rows (2 tiles of 16).
__global__ __launch_bounds__(256, 2) void k_gemm1(
    const int* __restrict__ state, const int* __restrict__ counts, const int* __restrict__ mp,
    const float* __restrict__ embed, const float* __restrict__ stab, const float* __restrict__ ctab,
    const unsigned short* __restrict__ W1p, const float* __restrict__ b1,
    unsigned short* __restrict__ h1b, float* __restrict__ gsum)
{
  __shared__ __align__(16) char smem[2 * 16384];     // 32 KiB W double-buffer
  __shared__ __align__(16) int  mp_lds[6272];        // 24.5 KiB mp[128][49]
  __shared__ float wsum[4][256];
  __shared__ float wsq[4][256];

  const int tid = threadIdx.x;
  const int w  = tid >> 6;
  const int l  = tid & 63;
  const int lr = l & 15;
  const int g  = l >> 4;
  const int rowbase = blockIdx.x * 128 + w * 32;
  const int arow0 = rowbase + lr;
  const int arow1 = rowbase + 16 + lr;

  const int st0 = state[arow0] * 32, st1 = state[arow1] * 32;
  const int ct0 = counts[arow0] * 16, ct1 = counts[arow1] * 16;
  const char* wsrc = (const char*)W1p;

  // stage this block's mp slice (coalesced 25088 B)
  {
    const char* mpsrc = (const char*)(mp + (size_t)blockIdx.x * 6272);
    #pragma unroll
    for (int it = 0; it < 7; ++it){
      int idx = it * 256 + tid;
      if (idx < 1568)
        GLOAD_LDS16(mpsrc + idx * 16, (char*)mp_lds + idx * 16);
    }
  }

  f32x4 xva[3][2], xvb[3][2];   // 3-slot ring: x(s), x(s+1), x(s+2)
  f32x4 acc0[16], acc1[16];
  #pragma unroll
  for (int i = 0; i < 16; ++i){ acc0[i] = (f32x4){0.f,0.f,0.f,0.f}; acc1[i] = acc0[i]; }

  // x gather-issue for step S into ring slot S%3 (2 row-tiles, 32B each = 4 vm loads)
  #define ISSUE_X(S) do {                                            \
    const float *p0_, *p1_;                                          \
    if ((S) == 0){ p0_ = stab + st0 + g * 8; p1_ = stab + st1 + g * 8; } \
    else if ((S) == 1 && g < 2){                                     \
      p0_ = ctab + ct0 + g * 8; p1_ = ctab + ct1 + g * 8;            \
    } else {                                                         \
      int m_ = 4 * (S) + g - 6;                                      \
      m_ = m_ < 0 ? 0 : (m_ > 48 ? 48 : m_);                         \
      p0_ = embed + ((mp_lds[(w * 32 + lr) * 49 + m_]      & 0xFFFFFF) << 3); \
      p1_ = embed + ((mp_lds[(w * 32 + 16 + lr) * 49 + m_] & 0xFFFFFF) << 3); \
    }                                                                \
    xva[(S)%3][0] = *(const f32x4*)p0_;  xvb[(S)%3][0] = *(const f32x4*)(p0_ + 4); \
    xva[(S)%3][1] = *(const f32x4*)p1_;  xvb[(S)%3][1] = *(const f32x4*)(p1_ + 4); \
  } while(0)

  // ---- prologue: mp+W(0)+x(0) issued; full drain; barrier (mp_lds valid); x(1) ----
  stage_w(wsrc, smem, 0, 0, w, l);
  ISSUE_X(0);
  asm volatile("s_waitcnt vmcnt(0)" ::: "memory");
  __builtin_amdgcn_sched_barrier(0);
  __builtin_amdgcn_s_barrier();
  ISSUE_X(1);
  asm volatile("" ::: "memory");
  __builtin_amdgcn_sched_barrier(0);

  bfrag ahi0, alo0, ahi1, alo1;

  #pragma unroll
  for (int s = 0; s < 14; ++s){
    // [A] stage W(s+1) (in flight across barriers)
    if (s < 13) stage_w(wsrc, smem, s + 1, (s + 1) & 1, w, l);
    asm volatile("" ::: "memory");
    __builtin_amdgcn_sched_barrier(0);

    // [B] consume x(s) -> frags; issue x(s+2)
    {
      f32x4 va0 = xva[s % 3][0], vb0 = xvb[s % 3][0];
      f32x4 va1 = xva[s % 3][1], vb1 = xvb[s % 3][1];
      if (s == 13 && g == 3){                      // K-pad 440..447 -> zeros
        va0 = (f32x4){0.f,0.f,0.f,0.f}; vb0 = va0; va1 = va0; vb1 = va0;
      }
      split2(va0, vb0, ahi0, alo0);
      split2(va1, vb1, ahi1, alo1);
    }
    if (s < 12) ISSUE_X(s + 2);

    // [C] retire stage(s): issue order guarantees in-order vmcnt retirement.
    // steady state: outstanding newer than stage(s) = x(s+1),stage(s+1),x(s+2) = 12
    __builtin_amdgcn_sched_barrier(0);
    if (s <= 11)      asm volatile("s_waitcnt vmcnt(12)" ::: "memory");
    else if (s == 12) asm volatile("s_waitcnt vmcnt(8)"  ::: "memory");
    else              asm volatile("s_waitcnt vmcnt(0)"  ::: "memory");
    __builtin_amdgcn_sched_barrier(0);
    __builtin_amdgcn_s_barrier();

    // [D] MFMA on buf[s&1]: 16 conflict-free ds_read_b128, 64 MFMA/step
    {
      const char* base = smem + (s & 1) * 16384 + l * 16;
      #pragma unroll
      for (int c = 0; c < 16; ++c){
        const bfrag bhi = *(const bfrag*)(base + c * 1024);
        acc0[c] = __builtin_amdgcn_mfma_f32_16x16x32_bf16(ahi0, bhi, acc0[c], 0, 0, 0);
        acc0[c] = __builtin_amdgcn_mfma_f32_16x16x32_bf16(alo0, bhi, acc0[c], 0, 0, 0);
        acc1[c] = __builtin_amdgcn_mfma_f32_16x16x32_bf16(ahi1, bhi, acc1[c], 0, 0, 0);
        acc1[c] = __builtin_amdgcn_mfma_f32_16x16x32_bf16(alo1, bhi, acc1[c], 0, 0, 0);
      }
    }

    // [E] barrier: buf[s&1] free for stage(s+2)
    __builtin_amdgcn_s_barrier();
  }
  #undef ISSUE_X

  // ---- epilogue: bias, h1(bf16) write (D: row=g*4+e, col=lr), stats -> atomics ----
  #pragma unroll
  for (int c = 0; c < 16; ++c){
    const int j = c * 16 + lr;
    const float bb = b1[j];
    float s = 0.f, q = 0.f;
    #pragma unroll
    for (int e = 0; e < 4; ++e){
      float h = acc0[c][e] + bb;
      s += h; q += h * h;
      h1b[(rowbase + g * 4 + e) * NCH + j] = cvt_bf16(h);
    }
    #pragma unroll
    for (int e = 0; e < 4; ++e){
      float h = acc1[c][e] + bb;
      s += h; q += h * h;
      h1b[(rowbase + 16 + g * 4 + e) * NCH + j] = cvt_bf16(h);
    }
    s += __shfl_xor(s, 16);  s += __shfl_xor(s, 32);
    q += __shfl_xor(q, 16);  q += __shfl_xor(q, 32);
    if (g == 0){ wsum[w][j] = s; wsq[w][j] = q; }
  }
  __syncthreads();
  {
    float s = wsum[0][tid] + wsum[1][tid] + wsum[2][tid] + wsum[3][tid];
    float q = wsq[0][tid]  + wsq[1][tid]  + wsq[2][tid]  + wsq[3][tid];
    atomicAdd(&gsum[tid], s);
    atomicAdd(&gsum[256 + tid], q);
  }
}

// ---- K2: BN(from gsum) + GEMM2 (2-pass MFMA, W2 in LDS) + ReLU + GEMM3 + ReLU + GEMM4 ----
// 512 blocks x 256 thr; block = 128 rows; wave w: 2 tiles of 16 rows (reuses staged W2).
__global__ __launch_bounds__(256, 3) void k_tail(
    const unsigned short* __restrict__ h1b, const float* __restrict__ gsum,
    const float* __restrict__ gamma, const float* __restrict__ beta,
    const unsigned short* __restrict__ W2p,
    const float* __restrict__ b2, const float* __restrict__ W3, const float* __restrict__ b3,
    const float* __restrict__ W4, const float* __restrict__ b4,
    float* __restrict__ out)
{
  __shared__ float ssl[512];
  __shared__ __align__(16) short w2s[16384];   // 32 KiB
  __shared__ float h2l[4][16][65];

  const int tid = threadIdx.x;
  const int w  = tid >> 6;
  const int l  = tid & 63;
  const int lr = l & 15;
  const int g  = l >> 4;
  const int rowbase = blockIdx.x * 128 + w * 32;

  // per-channel scale/shift from global sums
  {
    float su = gsum[tid];
    float sq = gsum[256 + tid];
    float mu  = su * (1.f / 65536.f);
    float var = sq * (1.f / 65536.f) - mu * mu;
    float sc  = gamma[tid] * rsqrtf(var + BN_EPS);
    ssl[tid]       = sc;
    ssl[256 + tid] = beta[tid] - mu * sc;
  }
  // stage W2p into LDS (32 KiB, coalesced)
  #pragma unroll
  for (int it = 0; it < 8; ++it)
    GLOAD_LDS16((const char*)W2p + (it * 256 + tid) * 16, (char*)w2s + (it * 256 + tid) * 16);
  __syncthreads();   // drains vmcnt + lgkmcnt

  const float b4v = b4[0];

  #pragma unroll
  for (int t = 0; t < 2; ++t){
    const int rowt = rowbase + t * 16;

    f32x4 acc[4];
    #pragma unroll
    for (int i = 0; i < 4; ++i) acc[i] = (f32x4){0.f, 0.f, 0.f, 0.f};

    #pragma unroll
    for (int s = 0; s < 8; ++s){
      const int kk = s * 32 + g * 8;
      bfrag hv = *(const bfrag*)(h1b + (rowt + lr) * 256 + kk);
      bfrag ahi, alo;
      #pragma unroll
      for (int e = 0; e < 8; ++e){
        float x = fmaf(bf16tof((unsigned short)hv[e]), ssl[kk + e], ssl[256 + kk + e]);
        unsigned short h0 = cvt_bf16(x);
        ahi[e] = (short)h0;
        alo[e] = (short)cvt_bf16(x - bf16tof(h0));
      }
      const char* base = (const char*)w2s + s * 4096 + l * 16;
      #pragma unroll
      for (int c = 0; c < 4; ++c){
        const bfrag bhi = *(const bfrag*)(base + c * 1024);
        acc[c] = __builtin_amdgcn_mfma_f32_16x16x32_bf16(ahi, bhi, acc[c], 0, 0, 0);
        acc[c] = __builtin_amdgcn_mfma_f32_16x16x32_bf16(alo, bhi, acc[c], 0, 0, 0);
      }
    }

    #pragma unroll
    for (int c = 0; c < 4; ++c){
      int j = c * 16 + lr;
      float bb = b2[j];
      #pragma unroll
      for (int e = 0; e < 4; ++e){
        float h = acc[c][e] + bb;
        h2l[w][g * 4 + e][j] = h > 0.f ? h : 0.f;
      }
    }

    float a3[4];
    #pragma unroll
    for (int t3 = 0; t3 < 4; ++t3) a3[t3] = b3[g * 4 + t3];
    #pragma unroll 4
    for (int k = 0; k < 64; ++k){
      float hv = h2l[w][lr][k];
      #pragma unroll
      for (int t3 = 0; t3 < 4; ++t3) a3[t3] += hv * W3[(g * 4 + t3) * 64 + k];
    }

    float p = 0.f;
    #pragma unroll
    for (int t3 = 0; t3 < 4; ++t3){
      float h = a3[t3] > 0.f ? a3[t3] : 0.f;
      p += h * W4[g * 4 + t3];
    }
    p += __shfl_xor(p, 16);
    p += __shfl_xor(p, 32);
    if (l < 16) out[rowt + lr] = p + b4v;
  }
}

extern "C" void kernel_launch(void* const* d_in, const int* in_sizes, int n_in,
                              void* d_out, int out_size, void* d_ws, size_t ws_size,
                              hipStream_t stream){
  const int*   state = (const int*)d_in[0];
  const int*   counts= (const int*)d_in[1];
  const int*   mp    = (const int*)d_in[2];
  const float* embed = (const float*)d_in[3];
  const float* stab  = (const float*)d_in[4];
  const float* ctab  = (const float*)d_in[5];
  const float* W1    = (const float*)d_in[6];
  const float* b1    = (const float*)d_in[7];
  const float* gamma = (const float*)d_in[8];
  const float* beta  = (const float*)d_in[9];
  const float* W2    = (const float*)d_in[10];
  const float* b2    = (const float*)d_in[11];
  const float* W3    = (const float*)d_in[12];
  const float* b3    = (const float*)d_in[13];
  const float* W4    = (const float*)d_in[14];
  const float* b4    = (const float*)d_in[15];
  float* out = (float*)d_out;

  char* ws = (char*)d_ws;
  unsigned short* h1bf = (unsigned short*)(ws);              // 32 MiB
  float* gsum          = (float*)(ws + 33554432);            // 2 KiB (sum|sq)
  unsigned short* W1p  = (unsigned short*)(ws + 33558528);   // 224 KiB
  unsigned short* W2p  = (unsigned short*)(ws + 33787904);   // 32 KiB

  k_prep <<<448, 256, 0, stream>>>(W1, W2, W1p, W2p, gsum);
  k_gemm1<<<512, 256, 0, stream>>>(state, counts, mp, embed, stab, ctab,
                                   W1p, b1, h1bf, gsum);
  k_tail <<<512, 256, 0, stream>>>(h1bf, gsum, gamma, beta, W2p,
                                   b2, W3, b3, W4, b4, out);
}